// Round 1
// baseline (104.358 us; speedup 1.0000x reference)
//
#include <hip/hip_runtime.h>

// Affine-grid bilinear sampler (spatial transformer), fp32.
// B=16, H=512, W=512, C=16. One thread per (pixel, float4 channel group).
// Memory-bound: ~256 MiB read + 256 MiB write.

constexpr int B_ = 16;
constexpr int H_ = 512;
constexpr int W_ = 512;
constexpr int C_ = 16;

__global__ __launch_bounds__(256) void spatial_sample_kernel(
    const float* __restrict__ img,    // [B,H,W,C]
    const float* __restrict__ theta,  // [B,2,3]
    float* __restrict__ out)          // [B,H,W,C]
{
    const int tid = blockIdx.x * blockDim.x + threadIdx.x;
    // total threads = B*H*W*(C/4) = 16*512*512*4 = 16,777,216 (exact grid fit)
    const int cg  = tid & 3;          // which float4 of the 16 channels
    const int pix = tid >> 2;
    const int xo  = pix & (W_ - 1);
    const int yo  = (pix >> 9) & (H_ - 1);
    const int b   = pix >> 18;

    // normalized grid coords (match np.linspace(-1,1,N): start + i*step)
    const float xn = fmaf((float)xo, 2.0f / (float)(W_ - 1), -1.0f);
    const float yn = fmaf((float)yo, 2.0f / (float)(H_ - 1), -1.0f);

    const float* th = theta + b * 6;
    const float gx = fmaf(th[0], xn, fmaf(th[1], yn, th[2]));
    const float gy = fmaf(th[3], xn, fmaf(th[4], yn, th[5]));

    // x = 0.5*((gx+1)*(max_x-1)), max_x = W-1
    const float x = 0.5f * ((gx + 1.0f) * (float)(W_ - 2));
    const float y = 0.5f * ((gy + 1.0f) * (float)(H_ - 2));

    int x0 = (int)floorf(x);
    int y0 = (int)floorf(y);
    x0 = min(max(x0, 0), W_ - 1);
    y0 = min(max(y0, 0), H_ - 1);
    const int x1 = min(x0 + 1, W_ - 1);
    const int y1 = min(y0 + 1, H_ - 1);

    const float x0f = (float)x0, x1f = (float)x1;
    const float y0f = (float)y0, y1f = (float)y1;
    const float wa = (x1f - x) * (y1f - y);
    const float wb = (x1f - x) * (y - y0f);
    const float wc = (x - x0f) * (y1f - y);
    const float wd = (x - x0f) * (y - y0f);

    const size_t base_b = (size_t)b * H_ * W_ * C_;
    const size_t ia = base_b + ((size_t)y0 * W_ + x0) * C_ + cg * 4;
    const size_t ib = base_b + ((size_t)y1 * W_ + x0) * C_ + cg * 4;
    const size_t ic = base_b + ((size_t)y0 * W_ + x1) * C_ + cg * 4;
    const size_t id = base_b + ((size_t)y1 * W_ + x1) * C_ + cg * 4;

    const float4 Ia = *reinterpret_cast<const float4*>(img + ia);
    const float4 Ib = *reinterpret_cast<const float4*>(img + ib);
    const float4 Ic = *reinterpret_cast<const float4*>(img + ic);
    const float4 Id = *reinterpret_cast<const float4*>(img + id);

    float4 r;
    r.x = wa * Ia.x + wb * Ib.x + wc * Ic.x + wd * Id.x;
    r.y = wa * Ia.y + wb * Ib.y + wc * Ic.y + wd * Id.y;
    r.z = wa * Ia.z + wb * Ib.z + wc * Ic.z + wd * Id.z;
    r.w = wa * Ia.w + wb * Ib.w + wc * Ic.w + wd * Id.w;

    *reinterpret_cast<float4*>(out + (size_t)pix * C_ + cg * 4) = r;
}

extern "C" void kernel_launch(void* const* d_in, const int* in_sizes, int n_in,
                              void* d_out, int out_size, void* d_ws, size_t ws_size,
                              hipStream_t stream) {
    const float* img   = (const float*)d_in[0];
    const float* theta = (const float*)d_in[1];
    float* out = (float*)d_out;

    const int total = B_ * H_ * W_ * (C_ / 4);   // 16,777,216
    const int block = 256;
    const int grid  = total / block;             // 65,536
    spatial_sample_kernel<<<grid, block, 0, stream>>>(img, theta, out);
}